// Round 8
// baseline (723.709 us; speedup 1.0000x reference)
//
#include <hip/hip_runtime.h>

// ELBO for the chromatin "Decoding" model — round 8.
// vs round 7 (447us; top-5 = harness's 640MB 0xAA ws-poison at 99us/iter —
// untouchable, already at HBM roofline):
//  * cuts+pois+finalize fused into ONE kernel (grid G + G/4): they're
//    independent -> overlap instead of serialize.
//  * frag sort re-keyed to GENE; pois is gene-major (4 genes/block, rw in
//    1KB LDS, counts 16KB LDS, latent from L2) -> small LDS so the fused
//    kernel isn't LDS-throttled, better occupancy than cell-major.
//  * scan2 fused into colscan via last-block ticket. 6 -> 4 dispatches.

#define TPB 256
#define CHUNK 4096
#define MAXG 4096
#define MAXN 1024
#define GPG 4
#define HALF_LOG_2PI 0.9189385332046727f

typedef short bf16x8 __attribute__((ext_vector_type(8)));
typedef float f32x4 __attribute__((ext_vector_type(4)));

static __device__ __forceinline__ unsigned short f2bf(float f) {
  unsigned u = __float_as_uint(f);
  u += 0x7fffu + ((u >> 16) & 1u);   // RNE
  return (unsigned short)(u >> 16);
}

// 256-thread block reduction; valid in thread 0 only.
static __device__ __forceinline__ float block_reduce(float v) {
  #pragma unroll
  for (int off = 32; off > 0; off >>= 1) v += __shfl_down(v, off, 64);
  __shared__ float wsum[4];
  if ((threadIdx.x & 63) == 0) wsum[threadIdx.x >> 6] = v;
  __syncthreads();
  return (threadIdx.x == 0) ? (wsum[0] + wsum[1] + wsum[2] + wsum[3]) : 0.f;
}

// ---------------- K1: per-chunk histograms + gene params + latbf + t2=0 ----
__global__ __launch_bounds__(TPB) void prep_hist_kernel(
    const int* __restrict__ cxg, const int* __restrict__ lix,
    unsigned* __restrict__ cntC, unsigned* __restrict__ cntF,
    const int* __restrict__ genes_oi,
    const float* __restrict__ loc_w, const float* __restrict__ scale_w,
    const float* __restrict__ logit_w, const float* __restrict__ latent,
    float4* __restrict__ gp, unsigned short* __restrict__ latbf,
    unsigned* __restrict__ ticket2,
    int K, int F, unsigned G, int B, int NL) {
  if ((int)blockIdx.x >= B) {
    if ((int)blockIdx.x == B && threadIdx.x == 0) *ticket2 = 0u;
    int idx = ((int)blockIdx.x - B) * TPB + threadIdx.x;
    int ngp = (int)G * 32;
    if (idx < ngp) {
      int g = idx >> 5, c = idx & 31;
      long long gene = genes_oi[g];
      float lv = loc_w[gene * 32 + c];
      float loc = 1.f / (1.f + __expf(-lv));
      float sc = 1e-5f + __expf(scale_w[gene * 32 + c]);
      gp[idx] = make_float4(loc, 1.f / sc, -__logf(sc) - HALF_LOG_2PI, logit_w[gene * 32 + c]);
    } else if (idx - ngp < NL) {
      latbf[idx - ngp] = f2bf(latent[idx - ngp]);
    }
    return;
  }
  __shared__ unsigned hC[MAXG];
  __shared__ unsigned hF[MAXG];
  for (int t = threadIdx.x; t < MAXG; t += TPB) { hC[t] = 0; hF[t] = 0; }
  __syncthreads();
  int i0 = blockIdx.x * CHUNK;
  for (int t = threadIdx.x; t < CHUNK; t += TPB) {
    int i = i0 + t;
    if (i < K) { unsigned ix = (unsigned)cxg[i]; atomicAdd(&hC[ix % G], 1u); }
    if (i < F) { unsigned v = (unsigned)lix[i]; atomicAdd(&hF[v % G], 1u); }
  }
  __syncthreads();
  size_t b = blockIdx.x;
  for (unsigned t = threadIdx.x; t < G; t += TPB) {
    cntC[b * G + t] = hC[t];
    cntF[b * G + t] = hF[t];
  }
}

// ---------------- K2: column scan (wave/column) + fused final scans --------
__global__ __launch_bounds__(TPB) void colscan_v3(
    unsigned* __restrict__ cntC, unsigned* __restrict__ cntF,
    unsigned* __restrict__ totC, unsigned* __restrict__ totF,
    unsigned* __restrict__ baseC, unsigned* __restrict__ baseF,
    int B, unsigned G, unsigned K, unsigned F,
    unsigned* __restrict__ ticket2, unsigned* __restrict__ ticket4, int NBLK) {
  unsigned wid = blockIdx.x * 4 + (threadIdx.x >> 6);
  int lane = threadIdx.x & 63;
  if (wid < 2 * G) {
    unsigned* col = (wid < G) ? (cntC + wid) : (cntF + (wid - G));
    unsigned* tot = (wid < G) ? (totC + wid) : (totF + (wid - G));
    unsigned base = 0;
    for (int b0 = 0; b0 < B; b0 += 64) {
      int b = b0 + lane;
      unsigned v = (b < B) ? col[(size_t)b * G] : 0u;
      unsigned inc = v;
      #pragma unroll
      for (int d = 1; d < 64; d <<= 1) {
        unsigned t2 = __shfl_up(inc, d, 64);
        if (lane >= d) inc += t2;
      }
      if (b < B) col[(size_t)b * G] = inc - v + base;
      base += __shfl(inc, 63, 64);
    }
    if (lane == 0) *tot = base;
  }
  __syncthreads();
  __shared__ unsigned sl;
  if (threadIdx.x == 0) {
    __threadfence();
    sl = atomicAdd(ticket2, 1u);
  }
  __syncthreads();
  if (sl == (unsigned)(NBLK - 1)) {
    __threadfence();
    int wv = threadIdx.x >> 6;
    if (wv == 0) {
      unsigned base = 0;
      for (int i0 = 0; i0 < (int)G; i0 += 64) {
        int i = i0 + lane;
        unsigned v = (i < (int)G) ? totC[i] : 0u;
        unsigned inc = v;
        #pragma unroll
        for (int d = 1; d < 64; d <<= 1) {
          unsigned t = __shfl_up(inc, d, 64);
          if (lane >= d) inc += t;
        }
        if (i < (int)G) baseC[i] = inc - v + base;
        base += __shfl(inc, 63, 64);
      }
      if (lane == 0) baseC[G] = K;
    } else if (wv == 1) {
      unsigned base = 0;
      for (int i0 = 0; i0 < (int)G; i0 += 64) {
        int i = i0 + lane;
        unsigned v = (i < (int)G) ? totF[i] : 0u;
        unsigned inc = v;
        #pragma unroll
        for (int d = 1; d < 64; d <<= 1) {
          unsigned t = __shfl_up(inc, d, 64);
          if (lane >= d) inc += t;
        }
        if (i < (int)G) baseF[i] = inc - v + base;
        base += __shfl(inc, 63, 64);
      }
      if (lane == 0) baseF[G] = F;
    } else if (threadIdx.x == 128) {
      *ticket4 = 0u;
    }
  }
}

// ---------------- K3: LDS-rank scatter (both sorts, gene-keyed) ------------
__global__ __launch_bounds__(TPB) void sort_pass3(
    const int* __restrict__ cxg, const int* __restrict__ lix,
    const float* __restrict__ xc, const int* __restrict__ gix,
    const unsigned* __restrict__ cntC, const unsigned* __restrict__ cntF,
    const unsigned* __restrict__ baseC, const unsigned* __restrict__ baseF,
    float2* __restrict__ pl, unsigned* __restrict__ fpl,
    int K, int F, unsigned G) {
  __shared__ unsigned cC[MAXG];
  __shared__ unsigned cF[MAXG];
  for (int t = threadIdx.x; t < MAXG; t += TPB) { cC[t] = 0; cF[t] = 0; }
  __syncthreads();
  int i0 = blockIdx.x * CHUNK;
  size_t b = blockIdx.x;
  for (int t = threadIdx.x; t < CHUNK; t += TPB) {
    int i = i0 + t;
    if (i < K) {
      unsigned ix = (unsigned)cxg[i];
      unsigned g = ix % G, n = ix / G;
      unsigned r = atomicAdd(&cC[g], 1u);
      unsigned pos = baseC[g] + cntC[b * G + g] + r;
      pl[pos] = make_float2(xc[i], __uint_as_float((n << 16) | (unsigned)gix[i]));
    }
    if (i < F) {
      unsigned v = (unsigned)lix[i];
      unsigned g = v % G, n = v / G;
      unsigned r = atomicAdd(&cF[g], 1u);
      fpl[baseF[g] + cntF[b * G + g] + r] = n;
    }
  }
}

// ---------------- K4: fused cuts (MFMA) + gene-major pois + finalize --------
__global__ __launch_bounds__(TPB) void main_kernel(
    const float2* __restrict__ pl, const unsigned* __restrict__ fpl,
    const unsigned short* __restrict__ latbf, const float* __restrict__ latent,
    const int* __restrict__ genes_oi, const int* __restrict__ cells_oi,
    const float* __restrict__ logit_weight, const float4* __restrict__ gp,
    const float* __restrict__ rho_weight, const float* __restrict__ rho_bias,
    const float* __restrict__ libsize,
    const unsigned* __restrict__ baseC, const unsigned* __restrict__ baseF,
    float* __restrict__ part, unsigned* __restrict__ ticket4,
    float* __restrict__ out, int N, unsigned G, int NB) {
  __shared__ __align__(16) float rwS[GPG * 64];
  __shared__ float rbS[GPG];
  __shared__ unsigned cnt[GPG * MAXN];
  const int bid = blockIdx.x;
  float lm = 0.f;

  if (bid < (int)G) {
    // -------- cuts: MFMA 16x16x32 bf16, block per gene --------
    const int g = bid;
    const int lane = threadIdx.x & 63;
    const int wv = threadIdx.x >> 6;
    const int quad = lane >> 4;
    const int r16 = lane & 15;

    const float* Wb = logit_weight + (size_t)genes_oi[g] * 2048;
    bf16x8 B0a, B1a, B0b, B1b;
    #pragma unroll
    for (int j = 0; j < 8; j++) {
      int l0 = quad * 8 + j;
      B0a[j] = (short)f2bf(Wb[l0 * 32 + r16]);
      B1a[j] = (short)f2bf(Wb[(l0 + 32) * 32 + r16]);
      B0b[j] = (short)f2bf(Wb[l0 * 32 + r16 + 16]);
      B1b[j] = (short)f2bf(Wb[(l0 + 32) * 32 + r16 + 16]);
    }

    const unsigned start = baseC[g], end = baseC[g + 1];
    const unsigned ntiles = (end - start + 15) >> 4;
    for (unsigned t = wv; t < ntiles; t += 4) {
      unsigned kk0 = start + t * 16;
      unsigned idx = kk0 + r16;
      float2 p = pl[idx < end ? idx : start];
      unsigned u = __float_as_uint(p.y);
      const unsigned short* lb = latbf + (size_t)(u >> 16) * 64;
      bf16x8 A0 = *(const bf16x8*)(lb + quad * 8);
      bf16x8 A1 = *(const bf16x8*)(lb + 32 + quad * 8);

      f32x4 acc0 = {0.f, 0.f, 0.f, 0.f};
      f32x4 acc1 = {0.f, 0.f, 0.f, 0.f};
      acc0 = __builtin_amdgcn_mfma_f32_16x16x32_bf16(A0, B0a, acc0, 0, 0, 0);
      acc0 = __builtin_amdgcn_mfma_f32_16x16x32_bf16(A1, B1a, acc0, 0, 0, 0);
      acc1 = __builtin_amdgcn_mfma_f32_16x16x32_bf16(A0, B0b, acc1, 0, 0, 0);
      acc1 = __builtin_amdgcn_mfma_f32_16x16x32_bf16(A1, B1b, acc1, 0, 0, 0);

      #pragma unroll
      for (int r = 0; r < 4; r++) {
        int cut = quad * 4 + r;
        float xr = __shfl(p.x, cut, 64);
        unsigned ur = (unsigned)__shfl((int)u, cut, 64);
        unsigned gi = ur & 0xffffu;
        float4 q0 = gp[(size_t)gi * 32 + r16];
        float4 q1 = gp[(size_t)gi * 32 + r16 + 16];
        float t0 = q0.w + acc0[r], t1 = q1.w + acc1[r];
        float z0 = (xr - q0.x) * q0.y, z1 = (xr - q1.x) * q1.y;
        float u0 = t0 + fmaf(-0.5f * z0, z0, q0.z);
        float u1 = t1 + fmaf(-0.5f * z1, z1, q1.z);
        float e1 = __expf(u0) + __expf(u1);
        float e2 = __expf(t0) + __expf(t1);
        #pragma unroll
        for (int d = 1; d < 16; d <<= 1) {
          e1 += __shfl_xor(e1, d, 64);
          e2 += __shfl_xor(e2, d, 64);
        }
        if (r16 == 0 && (kk0 + (unsigned)cut) < end) lm += __logf(e1) - __logf(e2);
      }
    }
  } else {
    // -------- pois: gene-major, 4 genes per block --------
    const int g0 = (bid - (int)G) * GPG;
    {
      int t = threadIdx.x;               // covers GPG*64 == 256
      int j = t >> 6, l = t & 63;
      rwS[t] = (g0 + j < (int)G) ? rho_weight[(size_t)genes_oi[g0 + j] * 64 + l] : 0.f;
      if (t < GPG) rbS[t] = (g0 + t < (int)G) ? rho_bias[genes_oi[g0 + t]] : 0.f;
    }
    for (int t = threadIdx.x; t < GPG * MAXN; t += TPB) cnt[t] = 0;
    __syncthreads();
    #pragma unroll
    for (int j = 0; j < GPG; j++) {
      if (g0 + j < (int)G) {
        unsigned s = baseF[g0 + j], e = baseF[g0 + j + 1];
        for (unsigned i = s + threadIdx.x; i < e; i += TPB)
          atomicAdd(&cnt[j * MAXN + fpl[i]], 1u);
      }
    }
    __syncthreads();
    for (int n = threadIdx.x; n < N; n += TPB) {
      const float4* latr = (const float4*)(latent + (size_t)n * 64);
      float rho[GPG] = {0.f, 0.f, 0.f, 0.f};
      #pragma unroll
      for (int i = 0; i < 16; i++) {
        float4 lv = latr[i];
        #pragma unroll
        for (int j = 0; j < GPG; j++) {
          float4 w = *(const float4*)(&rwS[j * 64 + i * 4]);
          rho[j] = fmaf(lv.x, w.x, rho[j]);
          rho[j] = fmaf(lv.y, w.y, rho[j]);
          rho[j] = fmaf(lv.z, w.z, rho[j]);
          rho[j] = fmaf(lv.w, w.w, rho[j]);
        }
      }
      float lib = libsize[cells_oi[n]];
      #pragma unroll
      for (int j = 0; j < GPG; j++) {
        if (g0 + j < (int)G) {
          float fe = rbS[j] * __expf(rho[j]) * lib;
          unsigned c = cnt[j * MAXN + n];
          float term = -fe;
          if (c) {
            float lf = 0.f;
            for (unsigned q2 = 2; q2 <= c; q2++) lf += __logf((float)q2);
            term += (float)c * __logf(fe) - lf;
          }
          lm += term;
        }
      }
    }
  }

  float bs = block_reduce(lm);
  __shared__ unsigned sl;
  if (threadIdx.x == 0) {
    part[bid] = bs;
    __threadfence();
    sl = atomicAdd(ticket4, 1u);
  }
  __syncthreads();
  if (sl == (unsigned)(NB - 1)) {
    __threadfence();
    float s = 0.f;
    for (int i = threadIdx.x; i < NB; i += TPB) s += part[i];
    float tot = block_reduce(s);
    if (threadIdx.x == 0) out[0] = -tot;
  }
}

extern "C" void kernel_launch(void* const* d_in, const int* in_sizes, int n_in,
                              void* d_out, int out_size, void* d_ws, size_t ws_size,
                              hipStream_t stream) {
  const int*   lix          = (const int*)d_in[0];
  const float* xc           = (const float*)d_in[1];
  const float* latent       = (const float*)d_in[2];
  const int*   genes_oi     = (const int*)d_in[3];
  const int*   cells_oi     = (const int*)d_in[4];
  const int*   cxg          = (const int*)d_in[5];
  const int*   gix          = (const int*)d_in[6];
  const float* loc_w        = (const float*)d_in[9];
  const float* scale_w      = (const float*)d_in[10];
  const float* logit_w      = (const float*)d_in[11];
  const float* logit_weight = (const float*)d_in[12];
  const float* rho_weight   = (const float*)d_in[13];
  const float* rho_bias     = (const float*)d_in[14];
  const float* libsize      = (const float*)d_in[15];
  float* out = (float*)d_out;

  const int F = in_sizes[0];
  const int K = in_sizes[1];
  const int N = in_sizes[2] / 64;
  const int G = in_sizes[3];
  const int NL = N * 64;

  const int M = (K > F) ? K : F;
  const int B = (M + CHUNK - 1) / CHUNK;           // sort chunks
  const int PGB = (G + GPG - 1) / GPG;             // pois blocks
  const int NB = G + PGB;                          // mega-kernel blocks
  const int GPB = (G * 32 + NL + TPB - 1) / TPB;   // gene-param blocks
  const int CSB = (2 * G + 3) / 4;                 // colscan blocks (4 waves ea)

  size_t off = 0;
  auto alloc = [&](size_t bytes) {
    size_t o = off;
    off = (off + bytes + 255) & ~(size_t)255;
    return o;
  };
  size_t cntC_off  = alloc((size_t)B * G * 4);
  size_t cntF_off  = alloc((size_t)B * G * 4);
  size_t totC_off  = alloc((size_t)G * 4);
  size_t totF_off  = alloc((size_t)G * 4);
  size_t baseC_off = alloc((size_t)(G + 1) * 4);
  size_t baseF_off = alloc((size_t)(G + 1) * 4);
  size_t pl_off    = alloc((size_t)K * 8);
  size_t fpl_off   = alloc((size_t)F * 4);
  size_t gp_off    = alloc((size_t)G * 32 * 16);
  size_t lb_off    = alloc((size_t)NL * 2);
  size_t part_off  = alloc((size_t)NB * 4);
  size_t tk2_off   = alloc(4);
  size_t tk4_off   = alloc(4);
  (void)ws_size;   // ~30 MB needed

  char* ws = (char*)d_ws;
  unsigned* cntC  = (unsigned*)(ws + cntC_off);
  unsigned* cntF  = (unsigned*)(ws + cntF_off);
  unsigned* totC  = (unsigned*)(ws + totC_off);
  unsigned* totF  = (unsigned*)(ws + totF_off);
  unsigned* baseC = (unsigned*)(ws + baseC_off);
  unsigned* baseF = (unsigned*)(ws + baseF_off);
  float2*   pl    = (float2*)(ws + pl_off);
  unsigned* fpl   = (unsigned*)(ws + fpl_off);
  float4*   gp    = (float4*)(ws + gp_off);
  unsigned short* latbf = (unsigned short*)(ws + lb_off);
  float*    part  = (float*)(ws + part_off);
  unsigned* ticket2 = (unsigned*)(ws + tk2_off);
  unsigned* ticket4 = (unsigned*)(ws + tk4_off);

  prep_hist_kernel<<<B + GPB, TPB, 0, stream>>>(
      cxg, lix, cntC, cntF, genes_oi, loc_w, scale_w, logit_w, latent,
      gp, latbf, ticket2, K, F, (unsigned)G, B, NL);
  colscan_v3<<<CSB, TPB, 0, stream>>>(
      cntC, cntF, totC, totF, baseC, baseF, B, (unsigned)G,
      (unsigned)K, (unsigned)F, ticket2, ticket4, CSB);
  sort_pass3<<<B, TPB, 0, stream>>>(cxg, lix, xc, gix, cntC, cntF, baseC, baseF,
                                    pl, fpl, K, F, (unsigned)G);
  main_kernel<<<NB, TPB, 0, stream>>>(
      pl, fpl, latbf, latent, genes_oi, cells_oi, logit_weight, gp,
      rho_weight, rho_bias, libsize, baseC, baseF, part, ticket4, out,
      N, (unsigned)G, NB);
}